// Round 1
// baseline (329.430 us; speedup 1.0000x reference)
//
#include <hip/hip_runtime.h>
#include <stdint.h>

// FluteLinear: out[m,n] = sum_k x[m,k] * tables[qweight[n,k]] * scales[n, k/128]
// M=16, N=14336, K=4096, GROUP=128 (G=32 groups).
// HBM-bound on qweight (235 MB int32). MFMA 16x16x32_f16: M=16 == BATCH.
// Decomposition: 896 n-tiles x 8 k-chunks(512) = 7168 wave-tasks
//              = 1792 blocks x 4 waves = exactly 7 blocks/CU.

#define K_DIM   4096
#define N_OUT   14336
#define G_CNT   32
#define KCHUNK  512
#define STEPS   16          // KCHUNK / 32

typedef _Float16 f16x8 __attribute__((ext_vector_type(8)));
typedef float    f32x4 __attribute__((ext_vector_type(4)));

__global__ __launch_bounds__(256, 4)
void FluteLinear_49658411876686_kernel(const float* __restrict__ x,
                                       const int*   __restrict__ qw,
                                       const float* __restrict__ scales,
                                       const float* __restrict__ tables,
                                       float*       __restrict__ out) {
    __shared__ float tab[16];
    const int tid = threadIdx.x;
    if (tid < 16) tab[tid] = tables[tid];
    __syncthreads();

    const int lane = tid & 63;
    const int wave = tid >> 6;
    const int wid  = blockIdx.x * 4 + wave;     // 0..7167
    const int nt   = wid >> 3;                  // 0..895  (n-tile)
    const int kc   = wid & 7;                   // 0..7    (k-chunk)
    const int n0   = nt << 4;
    const int k0   = kc * KCHUNK;

    const int row  = lane & 15;    // m for A-frag; n-offset for B-frag; col for D
    const int quad = lane >> 4;    // selects k-subgroup (quad*8 .. quad*8+7)

    // ---- A fragments: x[row][k0 + s*32 + quad*8 + j], j=0..7 (fp32 -> fp16) ----
    f16x8 a[STEPS];
    const float* xp = x + row * K_DIM + k0 + quad * 8;
    #pragma unroll
    for (int s = 0; s < STEPS; ++s) {
        const float4* p = (const float4*)(xp + s * 32);
        const float4 lo = p[0];
        const float4 hi = p[1];
        f16x8 af;
        af[0] = (_Float16)lo.x; af[1] = (_Float16)lo.y;
        af[2] = (_Float16)lo.z; af[3] = (_Float16)lo.w;
        af[4] = (_Float16)hi.x; af[5] = (_Float16)hi.y;
        af[6] = (_Float16)hi.z; af[7] = (_Float16)hi.w;
        a[s] = af;
    }

    // ---- per-lane n, its 4 group scales for this k-chunk ----
    const int n = n0 + row;
    const float4 sc = *(const float4*)(scales + n * G_CNT + kc * 4);
    const int* qp = qw + (size_t)n * K_DIM + k0 + quad * 8;

    f32x4 acc = {0.f, 0.f, 0.f, 0.f};
    #pragma unroll
    for (int g = 0; g < 4; ++g) {
        const float sg = (g == 0) ? sc.x : (g == 1) ? sc.y : (g == 2) ? sc.z : sc.w;
        #pragma unroll
        for (int ss = 0; ss < 4; ++ss) {
            const int s = g * 4 + ss;
            const int4* p = (const int4*)(qp + s * 32);
            const int4 qa = p[0];
            const int4 qb = p[1];
            f16x8 bfrag;
            bfrag[0] = (_Float16)(tab[qa.x & 15] * sg);
            bfrag[1] = (_Float16)(tab[qa.y & 15] * sg);
            bfrag[2] = (_Float16)(tab[qa.z & 15] * sg);
            bfrag[3] = (_Float16)(tab[qa.w & 15] * sg);
            bfrag[4] = (_Float16)(tab[qb.x & 15] * sg);
            bfrag[5] = (_Float16)(tab[qb.y & 15] * sg);
            bfrag[6] = (_Float16)(tab[qb.z & 15] * sg);
            bfrag[7] = (_Float16)(tab[qb.w & 15] * sg);
            acc = __builtin_amdgcn_mfma_f32_16x16x32_f16(a[s], bfrag, acc, 0, 0, 0);
        }
    }

    // ---- D layout: col = lane&15 (= n - n0), rowD = quad*4 + r (= m) ----
    float* op = out + n0 + row;
    #pragma unroll
    for (int r = 0; r < 4; ++r) {
        const int m = quad * 4 + r;
        atomicAdd(op + m * N_OUT, acc[r]);
    }
}

extern "C" void kernel_launch(void* const* d_in, const int* in_sizes, int n_in,
                              void* d_out, int out_size, void* d_ws, size_t ws_size,
                              hipStream_t stream) {
    const float* x      = (const float*)d_in[0];
    const int*   qw     = (const int*)  d_in[1];
    const float* scales = (const float*)d_in[2];
    const float* tables = (const float*)d_in[3];
    float*       out    = (float*)d_out;

    // k-split partials are atomically accumulated -> out must start at zero
    hipMemsetAsync(out, 0, (size_t)out_size * sizeof(float), stream);

    dim3 grid(1792);   // 1792 blocks * 4 waves = 7168 tasks = 896 n-tiles * 8 k-chunks
    dim3 block(256);
    FluteLinear_49658411876686_kernel<<<grid, block, 0, stream>>>(x, qw, scales, tables, out);
}